// Round 8
// baseline (58100.952 us; speedup 1.0000x reference)
//
#include <hip/hip_runtime.h>
#include <hip/hip_fp16.h>
#include <math.h>

#define B_   32
#define T_   400
#define BT_  12800
#define U_   1024
#define G4_  4096
#define TCH  100            // time-chunk length
#define NCH  4              // chunks per layer

__device__ __forceinline__ float sigf(float x){ return 1.0f/(1.0f+expf(-x)); }

// Diagnostic: ws too small -> fill out with 1000 so the failure mode is
// distinguishable from "kernel silently failed to launch" (absmax 0.5).
__global__ __launch_bounds__(256) void ws_sentinel_kernel(float* __restrict__ out, int n)
{
    const int i = blockIdx.x * 256 + threadIdx.x;
    if (i < n) out[i] = 1000.0f;
}

// ---------------- prenet: p = relu(relu(x@pw1+pb1)@pw2+pb2), p stored fp16 ----------------
__global__ __launch_bounds__(256) void prenet_kernel(
    const float* __restrict__ x, const float* __restrict__ pw1, const float* __restrict__ pb1,
    const float* __restrict__ pw2, const float* __restrict__ pb2, __half* __restrict__ p)
{
    __shared__ float xs[32*80];
    __shared__ float ys[32*256];
    const int r0 = blockIdx.x * 32;
    const int tid = threadIdx.x;
    for (int i = tid; i < 32*80; i += 256) xs[i] = x[r0*80 + i];
    __syncthreads();
    const int j = tid;   // 0..255
    float acc[32];
    #pragma unroll
    for (int r=0;r<32;r++) acc[r] = pb1[j];
    for (int k=0;k<80;k++){
        float w = pw1[k*256 + j];
        #pragma unroll
        for (int r=0;r<32;r++) acc[r] += xs[r*80+k]*w;
    }
    #pragma unroll
    for (int r=0;r<32;r++) ys[r*256+j] = fmaxf(acc[r], 0.0f);
    __syncthreads();
    #pragma unroll
    for (int r=0;r<32;r++) acc[r] = pb2[j];
    for (int k=0;k<256;k++){
        float w = pw2[k*256 + j];
        #pragma unroll
        for (int r=0;r<32;r++) acc[r] += ys[r*256+k]*w;
    }
    #pragma unroll
    for (int r=0;r<32;r++) p[(r0+r)*256 + j] = __float2half_rn(fmaxf(acc[r], 0.0f));
}

// ---------------- chunked GEMM: C[3200,4096] = A_rows(chunk) @ B[K,4096] ----------------
// A fp16 [12800,K] with global row g = b*400 + t0 + tt; local row l = b*100 + tt.
// C fp16 compact [3200,4096]. 64x64 tile, 256 thr, 4x4 per thread, K-tile 16.
template<int K>
__global__ __launch_bounds__(256) void gemm_chunk(
    const __half* __restrict__ A, const float* __restrict__ Bm,
    __half* __restrict__ C, int t0)
{
    __shared__ float As[16][68];   // [k][row]
    __shared__ float Bs[16][68];   // [k][col]
    const int bx = blockIdx.x;     // 64 col tiles
    const int by = blockIdx.y;     // 50 row tiles
    const int tid = threadIdx.x;
    const int tx = tid & 15, ty = tid >> 4;
    // A staging row mapping (chunk -> global)
    const int r_stage = tid >> 2;                 // 0..63
    const int l_row   = by*64 + r_stage;          // 0..3199
    const int bb      = l_row / TCH;              // const-div -> magic mul
    const int tt      = l_row - bb*TCH;
    const int g_row   = bb*T_ + t0 + tt;
    const int kk4     = (tid & 3) * 4;
    float acc[4][4] = {};
    for (int k0 = 0; k0 < K; k0 += 16) {
        {   // A tile 64x16 fp16 -> f32 transposed store
            const __half2* a2 = (const __half2*)&A[g_row*K + k0 + kk4];
            const float2 f0 = __half22float2(a2[0]);
            const float2 f1 = __half22float2(a2[1]);
            As[kk4+0][r_stage] = f0.x; As[kk4+1][r_stage] = f0.y;
            As[kk4+2][r_stage] = f1.x; As[kk4+3][r_stage] = f1.y;
        }
        {   // B tile 16x64 f32
            const int c4 = (tid & 15) * 4;
            const int kk = tid >> 4;
            *(float4*)&Bs[kk][c4] = *(const float4*)&Bm[(k0+kk)*G4_ + bx*64 + c4];
        }
        __syncthreads();
        #pragma unroll
        for (int kk = 0; kk < 16; kk++) {
            const float4 a4 = *(const float4*)&As[kk][ty*4];
            const float4 b4 = *(const float4*)&Bs[kk][tx*4];
            const float av[4] = {a4.x,a4.y,a4.z,a4.w};
            const float bv[4] = {b4.x,b4.y,b4.z,b4.w};
            #pragma unroll
            for (int i=0;i<4;i++)
                #pragma unroll
                for (int jj=0;jj<4;jj++) acc[i][jj] += av[i]*bv[jj];
        }
        __syncthreads();
    }
    const int row = by*64 + ty*4;
    const int col = bx*64 + tx*4;
    #pragma unroll
    for (int i=0;i<4;i++){
        __half2 o0 = __floats2half2_rn(acc[i][0], acc[i][1]);
        __half2 o1 = __floats2half2_rn(acc[i][2], acc[i][3]);
        __half2* cp = (__half2*)&C[(row+i)*G4_ + col];
        cp[0] = o0; cp[1] = o1;
    }
}

// ---------------- one MI-LSTM step ----------------
// grid 256 x 256 thr. Block owns 4 units x 4 gates x 32 batch. h state fp32
// double-buffered in global (h_in read by all blocks). xw chunk fp16.
__global__ __launch_bounds__(256) void lstm_step(
    const float* __restrict__ wh,     // [1024][4096] f32
    const __half* __restrict__ xwc,   // [3200][4096] fp16, row = b*100 + tr
    const float* __restrict__ aP,  const float* __restrict__ b1P,
    const float* __restrict__ b2P, const float* __restrict__ biasP,
    const float* __restrict__ h_in,   // [32][1024] f32
    float* __restrict__ h_out,        // [32][1024] f32
    float* __restrict__ c_st,         // [32][1024] f32
    __half* __restrict__ seq,         // [12800][1024] fp16, row = b*400 + t
    int t, int tr)
{
    __shared__ float  hs[32*1028];
    __shared__ float4 part[256];
    __shared__ float  hwx[32][4][4];
    const int tid = threadIdx.x;
    for (int i = tid; i < 8192; i += 256) {
        const int r = i >> 8;
        const int k = (i & 255) * 4;
        *(float4*)&hs[r*1028 + k] = *(const float4*)&h_in[i*4];
    }
    __syncthreads();

    const int g  = tid & 3;
    const int b  = (tid >> 2) & 31;
    const int kh = tid >> 7;
    const int bu0  = blockIdx.x * 4;
    const int col0 = g*1024 + bu0;

    float4 acc = make_float4(0.f,0.f,0.f,0.f);
    const float* hrow  = &hs[b*1028 + kh*512];
    const float* wbase = &wh[(kh*512)*G4_ + col0];
    for (int k = 0; k < 512; k += 4) {
        const float4 h4 = *(const float4*)&hrow[k];
        const float4 w0 = *(const float4*)&wbase[(k+0)*G4_];
        const float4 w1 = *(const float4*)&wbase[(k+1)*G4_];
        const float4 w2 = *(const float4*)&wbase[(k+2)*G4_];
        const float4 w3 = *(const float4*)&wbase[(k+3)*G4_];
        acc.x += h4.x*w0.x; acc.y += h4.x*w0.y; acc.z += h4.x*w0.z; acc.w += h4.x*w0.w;
        acc.x += h4.y*w1.x; acc.y += h4.y*w1.y; acc.z += h4.y*w1.z; acc.w += h4.y*w1.w;
        acc.x += h4.z*w2.x; acc.y += h4.z*w2.y; acc.z += h4.z*w2.z; acc.w += h4.z*w2.w;
        acc.x += h4.w*w3.x; acc.y += h4.w*w3.y; acc.z += h4.w*w3.z; acc.w += h4.w*w3.w;
    }
    part[tid] = acc;
    __syncthreads();
    if (tid < 128) {
        const float4 x0 = part[tid];
        const float4 x1 = part[tid + 128];
        float4 s = make_float4(x0.x+x1.x, x0.y+x1.y, x0.z+x1.z, x0.w+x1.w);
        *(float4*)&hwx[tid>>2][tid&3][0] = s;
    }
    __syncthreads();
    if (tid < 128) {
        const int bb = tid >> 2;
        const int j  = tid & 3;
        const int u  = bu0 + j;
        const float hw_i = hwx[bb][0][j];
        const float hw_f = hwx[bb][1][j];
        const float hw_g = hwx[bb][2][j];
        const float hw_o = hwx[bb][3][j];
        const __half* xwrow = &xwc[(bb*TCH + tr) * G4_];
        const float x_i = __half2float(xwrow[0*1024 + u]);
        const float x_f = __half2float(xwrow[1*1024 + u]);
        const float x_g = __half2float(xwrow[2*1024 + u]);
        const float x_o = __half2float(xwrow[3*1024 + u]);
        const int ci = 0*1024+u, cf = 1*1024+u, cg = 2*1024+u, co = 3*1024+u;
        const float z_i = aP[ci]*x_i*hw_i + b1P[ci]*x_i + b2P[ci]*hw_i + biasP[ci];
        const float z_f = aP[cf]*x_f*hw_f + b1P[cf]*x_f + b2P[cf]*hw_f + biasP[cf];
        const float z_g = aP[cg]*x_g*hw_g + b1P[cg]*x_g + b2P[cg]*hw_g + biasP[cg];
        const float z_o = aP[co]*x_o*hw_o + b1P[co]*x_o + b2P[co]*hw_o + biasP[co];
        const float c_old  = c_st[bb*1024 + u];
        const float c_new  = sigf(z_f)*c_old + sigf(z_i)*tanhf(z_g);
        const float h_new  = sigf(z_o)*tanhf(c_new);
        const float c_outv = 0.1f*c_old + 0.9f*c_new;
        const float h_prev = hs[bb*1028 + u];
        const float h_outv = 0.1f*h_prev + 0.9f*h_new;
        c_st[bb*1024 + u]  = c_outv;
        h_out[bb*1024 + u] = h_outv;
        seq[(bb*T_ + t)*1024 + u] = __float2half_rn(h_outv);
    }
}

// ---------------- final: out = concat(h2@fw+fb, sigmoid(h2@sw+sb)) ----------------
__global__ __launch_bounds__(256) void final_kernel(
    const __half* __restrict__ h2, const float* __restrict__ fw, const float* __restrict__ fb,
    const float* __restrict__ sw, const float* __restrict__ sb, float* __restrict__ out)
{
    __shared__ float hs2[32*1028];
    const int r0 = blockIdx.x * 32;
    const int tid = threadIdx.x;
    for (int i = tid; i < 8192; i += 256) {
        const int r = i >> 8;
        const int k = (i & 255) * 4;
        const __half2* hp = (const __half2*)&h2[(r0+r)*1024 + k];
        const float2 f0 = __half22float2(hp[0]);
        const float2 f1 = __half22float2(hp[1]);
        hs2[r*1028 + k+0] = f0.x; hs2[r*1028 + k+1] = f0.y;
        hs2[r*1028 + k+2] = f1.x; hs2[r*1028 + k+3] = f1.y;
    }
    __syncthreads();
    const int j = tid;
    if (j < 161) {
        const bool is_stop = (j == 160);
        float acc[32];
        const float bias = is_stop ? sb[0] : fb[j];
        #pragma unroll
        for (int r=0;r<32;r++) acc[r] = bias;
        for (int k=0;k<1024;k++){
            const float w = is_stop ? sw[k] : fw[k*160 + j];
            #pragma unroll
            for (int r=0;r<32;r++) acc[r] += hs2[r*1028 + k] * w;
        }
        #pragma unroll
        for (int r=0;r<32;r++){
            float v = acc[r];
            if (is_stop) v = sigf(v);
            out[(size_t)(r0+r)*161 + j] = v;
        }
    }
}

extern "C" void kernel_launch(void* const* d_in, const int* in_sizes, int n_in,
                              void* d_out, int out_size, void* d_ws, size_t ws_size,
                              hipStream_t stream)
{
    const float* x    = (const float*)d_in[0];
    const float* pw1  = (const float*)d_in[1];
    const float* pb1  = (const float*)d_in[2];
    const float* pw2  = (const float*)d_in[3];
    const float* pb2  = (const float*)d_in[4];
    const float* wx1  = (const float*)d_in[5];
    const float* wh1  = (const float*)d_in[6];
    const float* a1   = (const float*)d_in[7];
    const float* b11  = (const float*)d_in[8];
    const float* b21  = (const float*)d_in[9];
    const float* bias1= (const float*)d_in[10];
    const float* wx2  = (const float*)d_in[11];
    const float* wh2  = (const float*)d_in[12];
    const float* a2   = (const float*)d_in[13];
    const float* b12  = (const float*)d_in[14];
    const float* b22  = (const float*)d_in[15];
    const float* bias2= (const float*)d_in[16];
    const float* sw   = (const float*)d_in[17];
    const float* sb   = (const float*)d_in[18];
    const float* fw   = (const float*)d_in[19];
    const float* fb   = (const float*)d_in[20];
    float* out = (float*)d_out;

    // ws layout (bytes); total = 59,375,616 B (~56.6 MiB)
    char* base = (char*)d_ws;
    __half* hseq = (__half*)(base);                    // 12800*1024*2 = 26,214,400  (h1 then h2)
    __half* xwc  = (__half*)(base + 26214400);         //  3200*4096*2 = 26,214,400  (chunk xw)
    __half* p    = (__half*)(base + 52428800);         // 12800*256*2  =  6,553,600
    float*  hb0  = (float*) (base + 58982400);         // 32*1024*4    =    131,072
    float*  hb1  = (float*) (base + 59113472);         //    131,072
    float*  cb   = (float*) (base + 59244544);         //    131,072  -> end 59,375,616
    const size_t NEED = 59375616;
    if (ws_size < NEED) {
        // Sentinel: absmax ~1000 signals "ws too small" unambiguously.
        ws_sentinel_kernel<<<(out_size + 255) / 256, 256, 0, stream>>>(out, out_size);
        return;
    }

    prenet_kernel<<<400, 256, 0, stream>>>(x, pw1, pb1, pw2, pb2, p);

    // ---- layer 1 ----
    hipMemsetAsync(hb0, 0, (size_t)3*32768*sizeof(float), stream);
    for (int c = 0; c < NCH; c++) {
        const int t0 = c * TCH;
        gemm_chunk<256><<<dim3(64, 50), 256, 0, stream>>>(p, wx1, xwc, t0);
        for (int tt = 0; tt < TCH; tt++) {
            const int t = t0 + tt;
            float* hin = (t & 1) ? hb1 : hb0;
            float* hou = (t & 1) ? hb0 : hb1;
            lstm_step<<<256, 256, 0, stream>>>(wh1, xwc, a1, b11, b21, bias1,
                                               hin, hou, cb, hseq, t, tt);
        }
    }

    // ---- layer 2 (reads hseq chunk c as A, then steps overwrite chunk c with h2) ----
    hipMemsetAsync(hb0, 0, (size_t)3*32768*sizeof(float), stream);
    for (int c = 0; c < NCH; c++) {
        const int t0 = c * TCH;
        gemm_chunk<1024><<<dim3(64, 50), 256, 0, stream>>>(hseq, wx2, xwc, t0);
        for (int tt = 0; tt < TCH; tt++) {
            const int t = t0 + tt;
            float* hin = (t & 1) ? hb1 : hb0;
            float* hou = (t & 1) ? hb0 : hb1;
            lstm_step<<<256, 256, 0, stream>>>(wh2, xwc, a2, b12, b22, bias2,
                                               hin, hou, cb, hseq, t, tt);
        }
    }

    final_kernel<<<400, 256, 0, stream>>>(hseq, fw, fb, sw, sb, out);
}

// Round 9
// 17521.684 us; speedup vs baseline: 3.3159x; 3.3159x over previous
//
#include <hip/hip_runtime.h>
#include <hip/hip_fp16.h>
#include <math.h>

#define B_   32
#define T_   400
#define BT_  12800
#define U_   1024
#define G4_  4096
#define TCH  100            // time-chunk length
#define NCH  4              // chunks per layer
#define HS_  1032           // fp16 h stride in LDS (2-way max on reads)
#define WS_  1028           // fp32 w stride in LDS

__device__ __forceinline__ float sigf(float x){ return 1.0f/(1.0f+expf(-x)); }
__device__ __forceinline__ float2 h2f2(int u){
    __half2 h = __builtin_bit_cast(__half2, u);
    return __half22float2(h);
}
__device__ __forceinline__ int f2h2(float a, float b){
    __half2 h = __floats2half2_rn(a, b);
    return __builtin_bit_cast(int, h);
}

// Diagnostic: ws too small -> fill out with 1000 (distinguishable from
// "kernel silently failed to launch", which leaves absmax at 0.5).
__global__ __launch_bounds__(256) void ws_sentinel_kernel(float* __restrict__ out, int n)
{
    const int i = blockIdx.x * 256 + threadIdx.x;
    if (i < n) out[i] = 1000.0f;
}

// ---------------- one-time: whT[c][k] = (fp16) wh[k][c]  (wh [1024][4096]) ----
__global__ __launch_bounds__(256) void transpose_fp16_kernel(
    const float* __restrict__ W, __half* __restrict__ WT)
{
    __shared__ float tile[64][65];
    const int bx = blockIdx.x;   // 64 col tiles
    const int by = blockIdx.y;   // 16 row tiles
    const int tid = threadIdx.x;
    for (int i = tid; i < 1024; i += 256) {        // 64 rows x 16 float4
        const int r  = i >> 4;
        const int c4 = (i & 15) * 4;
        float4 v = *(const float4*)&W[(by*64 + r)*G4_ + bx*64 + c4];
        tile[c4+0][r] = v.x; tile[c4+1][r] = v.y;
        tile[c4+2][r] = v.z; tile[c4+3][r] = v.w;
    }
    __syncthreads();
    for (int i = tid; i < 512; i += 256) {         // 64 cols x 8 chunks of 8
        const int c  = i >> 3;
        const int r8 = (i & 7) * 8;
        int4 pk;
        pk.x = f2h2(tile[c][r8+0], tile[c][r8+1]);
        pk.y = f2h2(tile[c][r8+2], tile[c][r8+3]);
        pk.z = f2h2(tile[c][r8+4], tile[c][r8+5]);
        pk.w = f2h2(tile[c][r8+6], tile[c][r8+7]);
        *(int4*)&WT[(bx*64 + c)*U_ + by*64 + r8] = pk;
    }
}

// ---------------- prenet: p = relu(relu(x@pw1+pb1)@pw2+pb2), p stored fp16 ----
__global__ __launch_bounds__(256) void prenet_kernel(
    const float* __restrict__ x, const float* __restrict__ pw1, const float* __restrict__ pb1,
    const float* __restrict__ pw2, const float* __restrict__ pb2, __half* __restrict__ p)
{
    __shared__ float xs[32*80];
    __shared__ float ys[32*256];
    const int r0 = blockIdx.x * 32;
    const int tid = threadIdx.x;
    for (int i = tid; i < 32*80; i += 256) xs[i] = x[r0*80 + i];
    __syncthreads();
    const int j = tid;
    float acc[32];
    #pragma unroll
    for (int r=0;r<32;r++) acc[r] = pb1[j];
    for (int k=0;k<80;k++){
        float w = pw1[k*256 + j];
        #pragma unroll
        for (int r=0;r<32;r++) acc[r] += xs[r*80+k]*w;
    }
    #pragma unroll
    for (int r=0;r<32;r++) ys[r*256+j] = fmaxf(acc[r], 0.0f);
    __syncthreads();
    #pragma unroll
    for (int r=0;r<32;r++) acc[r] = pb2[j];
    for (int k=0;k<256;k++){
        float w = pw2[k*256 + j];
        #pragma unroll
        for (int r=0;r<32;r++) acc[r] += ys[r*256+k]*w;
    }
    #pragma unroll
    for (int r=0;r<32;r++) p[(r0+r)*256 + j] = __float2half_rn(fmaxf(acc[r], 0.0f));
}

// ---------------- chunked GEMM: C[3200,4096] = A_rows(chunk) @ B[K,4096] -------
template<int K>
__global__ __launch_bounds__(256) void gemm_chunk(
    const __half* __restrict__ A, const float* __restrict__ Bm,
    __half* __restrict__ C, int t0)
{
    __shared__ float As[16][68];
    __shared__ float Bs[16][68];
    const int bx = blockIdx.x;
    const int by = blockIdx.y;
    const int tid = threadIdx.x;
    const int tx = tid & 15, ty = tid >> 4;
    const int r_stage = tid >> 2;
    const int l_row   = by*64 + r_stage;
    const int bb      = l_row / TCH;
    const int tt      = l_row - bb*TCH;
    const int g_row   = bb*T_ + t0 + tt;
    const int kk4     = (tid & 3) * 4;
    float acc[4][4] = {};
    for (int k0 = 0; k0 < K; k0 += 16) {
        {
            const __half2* a2 = (const __half2*)&A[g_row*K + k0 + kk4];
            const float2 f0 = __half22float2(a2[0]);
            const float2 f1 = __half22float2(a2[1]);
            As[kk4+0][r_stage] = f0.x; As[kk4+1][r_stage] = f0.y;
            As[kk4+2][r_stage] = f1.x; As[kk4+3][r_stage] = f1.y;
        }
        {
            const int c4 = (tid & 15) * 4;
            const int kk = tid >> 4;
            *(float4*)&Bs[kk][c4] = *(const float4*)&Bm[(k0+kk)*G4_ + bx*64 + c4];
        }
        __syncthreads();
        #pragma unroll
        for (int kk = 0; kk < 16; kk++) {
            const float4 a4 = *(const float4*)&As[kk][ty*4];
            const float4 b4 = *(const float4*)&Bs[kk][tx*4];
            const float av[4] = {a4.x,a4.y,a4.z,a4.w};
            const float bv[4] = {b4.x,b4.y,b4.z,b4.w};
            #pragma unroll
            for (int i=0;i<4;i++)
                #pragma unroll
                for (int jj=0;jj<4;jj++) acc[i][jj] += av[i]*bv[jj];
        }
        __syncthreads();
    }
    const int row = by*64 + ty*4;
    const int col = bx*64 + tx*4;
    #pragma unroll
    for (int i=0;i<4;i++){
        __half2 o0 = __floats2half2_rn(acc[i][0], acc[i][1]);
        __half2 o1 = __floats2half2_rn(acc[i][2], acc[i][3]);
        __half2* cp = (__half2*)&C[(row+i)*G4_ + col];
        cp[0] = o0; cp[1] = o1;
    }
}

// ---------------- one MI-LSTM step (rebuilt) ----------------
// 256 blocks x 256 thr, block owns units [bu0,bu0+4) x 4 gates x 32 batch.
// Weights: whT fp16 global (coalesced rows) -> fp32 LDS per step.
// h: fp32 global -> fp16 LDS. Inner loop: pure LDS + FMA.
// Thread map: b=tid>>3 (0..31), g=(tid>>1)&3, kh=tid&1 (K half).
__global__ __launch_bounds__(256) void lstm_step(
    const __half* __restrict__ whT,   // [4096][1024] fp16, whT[c][k]
    const __half* __restrict__ xwc,   // [3200][4096] fp16, row = b*100 + tr
    const float* __restrict__ aP,  const float* __restrict__ b1P,
    const float* __restrict__ b2P, const float* __restrict__ biasP,
    const float* __restrict__ h_in,   // [32][1024] f32
    float* __restrict__ h_out,        // [32][1024] f32
    float* __restrict__ c_st,         // [32][1024] f32
    __half* __restrict__ seq,         // [12800][1024] fp16, row = b*400 + t
    int t, int tr)
{
    __shared__ __half hs[32*HS_];     // 66,048 B
    __shared__ float  wl[16*WS_];     // 65,792 B
    __shared__ float  hwx[32][4][4];  //  2,048 B
    const int tid = threadIdx.x;
    const int bu0 = blockIdx.x * 4;

    // stage h: fp32 global -> fp16 LDS (16 iters: 2x float4 load, 1x b128 store)
    for (int i = tid; i < 4096; i += 256) {
        const int r  = i >> 7;
        const int k8 = (i & 127) * 8;
        const float4 f0 = *(const float4*)&h_in[r*U_ + k8];
        const float4 f1 = *(const float4*)&h_in[r*U_ + k8 + 4];
        int4 pk;
        pk.x = f2h2(f0.x, f0.y); pk.y = f2h2(f0.z, f0.w);
        pk.z = f2h2(f1.x, f1.y); pk.w = f2h2(f1.z, f1.w);
        *(int4*)&hs[r*HS_ + k8] = pk;
    }
    // stage w: whT fp16 global (contiguous rows) -> fp32 LDS (8 iters)
    for (int i = tid; i < 2048; i += 256) {
        const int rr = i >> 7;                   // 0..15 = g*4+j
        const int k8 = (i & 127) * 8;
        const int c  = (rr >> 2)*U_ + bu0 + (rr & 3);
        const int4 hv = *(const int4*)&whT[c*U_ + k8];
        const float2 f0 = h2f2(hv.x), f1 = h2f2(hv.y), f2 = h2f2(hv.z), f3 = h2f2(hv.w);
        *(float4*)&wl[rr*WS_ + k8]     = make_float4(f0.x, f0.y, f1.x, f1.y);
        *(float4*)&wl[rr*WS_ + k8 + 4] = make_float4(f2.x, f2.y, f3.x, f3.y);
    }
    __syncthreads();

    const int b  = tid >> 3;
    const int g  = (tid >> 1) & 3;
    const int kh = tid & 1;
    const float*  w0 = &wl[(g*4+0)*WS_ + kh*512];
    const float*  w1 = &wl[(g*4+1)*WS_ + kh*512];
    const float*  w2 = &wl[(g*4+2)*WS_ + kh*512];
    const float*  w3 = &wl[(g*4+3)*WS_ + kh*512];
    const __half* hr = &hs[b*HS_ + kh*512];

    float4 acc = make_float4(0.f,0.f,0.f,0.f);
    for (int k = 0; k < 512; k += 8) {
        const int4 hv = *(const int4*)&hr[k];
        const float2 hA = h2f2(hv.x), hB = h2f2(hv.y), hC = h2f2(hv.z), hD = h2f2(hv.w);
        const float hk0=hA.x, hk1=hA.y, hk2=hB.x, hk3=hB.y,
                    hk4=hC.x, hk5=hC.y, hk6=hD.x, hk7=hD.y;
        const float4 a0 = *(const float4*)&w0[k], a1 = *(const float4*)&w0[k+4];
        const float4 b0 = *(const float4*)&w1[k], b1 = *(const float4*)&w1[k+4];
        const float4 c0 = *(const float4*)&w2[k], c1 = *(const float4*)&w2[k+4];
        const float4 d0 = *(const float4*)&w3[k], d1 = *(const float4*)&w3[k+4];
        acc.x += hk0*a0.x + hk1*a0.y + hk2*a0.z + hk3*a0.w
               + hk4*a1.x + hk5*a1.y + hk6*a1.z + hk7*a1.w;
        acc.y += hk0*b0.x + hk1*b0.y + hk2*b0.z + hk3*b0.w
               + hk4*b1.x + hk5*b1.y + hk6*b1.z + hk7*b1.w;
        acc.z += hk0*c0.x + hk1*c0.y + hk2*c0.z + hk3*c0.w
               + hk4*c1.x + hk5*c1.y + hk6*c1.z + hk7*c1.w;
        acc.w += hk0*d0.x + hk1*d0.y + hk2*d0.z + hk3*d0.w
               + hk4*d1.x + hk5*d1.y + hk6*d1.z + hk7*d1.w;
    }
    // reduce K-halves: kh pairs are adjacent lanes
    acc.x += __shfl_xor(acc.x, 1);
    acc.y += __shfl_xor(acc.y, 1);
    acc.z += __shfl_xor(acc.z, 1);
    acc.w += __shfl_xor(acc.w, 1);
    if (kh == 0) *(float4*)&hwx[b][g][0] = acc;
    __syncthreads();

    if (tid < 128) {
        const int bb = tid >> 2;
        const int j  = tid & 3;
        const int u  = bu0 + j;
        const float hw_i = hwx[bb][0][j];
        const float hw_f = hwx[bb][1][j];
        const float hw_g = hwx[bb][2][j];
        const float hw_o = hwx[bb][3][j];
        const __half* xwrow = &xwc[(bb*TCH + tr) * G4_];
        const float x_i = __half2float(xwrow[0*U_ + u]);
        const float x_f = __half2float(xwrow[1*U_ + u]);
        const float x_g = __half2float(xwrow[2*U_ + u]);
        const float x_o = __half2float(xwrow[3*U_ + u]);
        const int ci = 0*U_+u, cf = 1*U_+u, cg = 2*U_+u, co = 3*U_+u;
        const float z_i = aP[ci]*x_i*hw_i + b1P[ci]*x_i + b2P[ci]*hw_i + biasP[ci];
        const float z_f = aP[cf]*x_f*hw_f + b1P[cf]*x_f + b2P[cf]*hw_f + biasP[cf];
        const float z_g = aP[cg]*x_g*hw_g + b1P[cg]*x_g + b2P[cg]*hw_g + biasP[cg];
        const float z_o = aP[co]*x_o*hw_o + b1P[co]*x_o + b2P[co]*hw_o + biasP[co];
        const float c_old  = c_st[bb*U_ + u];
        const float c_new  = sigf(z_f)*c_old + sigf(z_i)*tanhf(z_g);
        const float h_new  = sigf(z_o)*tanhf(c_new);
        const float c_outv = 0.1f*c_old + 0.9f*c_new;
        const float h_prev = h_in[bb*U_ + u];          // fp32 state, exact carry
        const float h_outv = 0.1f*h_prev + 0.9f*h_new;
        c_st[bb*U_ + u]  = c_outv;
        h_out[bb*U_ + u] = h_outv;
        seq[(bb*T_ + t)*U_ + u] = __float2half_rn(h_outv);
    }
}

// ---------------- final: out = concat(h2@fw+fb, sigmoid(h2@sw+sb)) -------------
__global__ __launch_bounds__(256) void final_kernel(
    const __half* __restrict__ h2, const float* __restrict__ fw, const float* __restrict__ fb,
    const float* __restrict__ sw, const float* __restrict__ sb, float* __restrict__ out)
{
    __shared__ float hs2[32*1028];
    const int r0 = blockIdx.x * 32;
    const int tid = threadIdx.x;
    for (int i = tid; i < 8192; i += 256) {
        const int r = i >> 8;
        const int k = (i & 255) * 4;
        const __half2* hp = (const __half2*)&h2[(r0+r)*1024 + k];
        const float2 f0 = __half22float2(hp[0]);
        const float2 f1 = __half22float2(hp[1]);
        hs2[r*1028 + k+0] = f0.x; hs2[r*1028 + k+1] = f0.y;
        hs2[r*1028 + k+2] = f1.x; hs2[r*1028 + k+3] = f1.y;
    }
    __syncthreads();
    const int j = tid;
    if (j < 161) {
        const bool is_stop = (j == 160);
        float acc[32];
        const float bias = is_stop ? sb[0] : fb[j];
        #pragma unroll
        for (int r=0;r<32;r++) acc[r] = bias;
        for (int k=0;k<1024;k++){
            const float w = is_stop ? sw[k] : fw[k*160 + j];
            #pragma unroll
            for (int r=0;r<32;r++) acc[r] += hs2[r*1028 + k] * w;
        }
        #pragma unroll
        for (int r=0;r<32;r++){
            float v = acc[r];
            if (is_stop) v = sigf(v);
            out[(size_t)(r0+r)*161 + j] = v;
        }
    }
}

extern "C" void kernel_launch(void* const* d_in, const int* in_sizes, int n_in,
                              void* d_out, int out_size, void* d_ws, size_t ws_size,
                              hipStream_t stream)
{
    const float* x    = (const float*)d_in[0];
    const float* pw1  = (const float*)d_in[1];
    const float* pb1  = (const float*)d_in[2];
    const float* pw2  = (const float*)d_in[3];
    const float* pb2  = (const float*)d_in[4];
    const float* wx1  = (const float*)d_in[5];
    const float* wh1  = (const float*)d_in[6];
    const float* a1   = (const float*)d_in[7];
    const float* b11  = (const float*)d_in[8];
    const float* b21  = (const float*)d_in[9];
    const float* bias1= (const float*)d_in[10];
    const float* wx2  = (const float*)d_in[11];
    const float* wh2  = (const float*)d_in[12];
    const float* a2   = (const float*)d_in[13];
    const float* b12  = (const float*)d_in[14];
    const float* b22  = (const float*)d_in[15];
    const float* bias2= (const float*)d_in[16];
    const float* sw   = (const float*)d_in[17];
    const float* sb   = (const float*)d_in[18];
    const float* fw   = (const float*)d_in[19];
    const float* fb   = (const float*)d_in[20];
    float* out = (float*)d_out;

    // ws layout (bytes); total = 76,152,832 B (~72.6 MiB)
    char* base = (char*)d_ws;
    __half* hseq = (__half*)(base);                    // 26,214,400
    __half* xwc  = (__half*)(base + 26214400);         // 26,214,400
    __half* p    = (__half*)(base + 52428800);         //  6,553,600
    float*  hb0  = (float*) (base + 58982400);         //    131,072
    float*  hb1  = (float*) (base + 59113472);         //    131,072
    float*  cb   = (float*) (base + 59244544);         //    131,072
    __half* whT1 = (__half*)(base + 59375616);         //  8,388,608
    __half* whT2 = (__half*)(base + 67764224);         //  8,388,608 -> 76,152,832
    const size_t NEED = 76152832;
    if (ws_size < NEED) {
        ws_sentinel_kernel<<<(out_size + 255) / 256, 256, 0, stream>>>(out, out_size);
        return;
    }

    // one-time weight prep (runs every call; trivial cost)
    transpose_fp16_kernel<<<dim3(64,16), 256, 0, stream>>>(wh1, whT1);
    transpose_fp16_kernel<<<dim3(64,16), 256, 0, stream>>>(wh2, whT2);

    prenet_kernel<<<400, 256, 0, stream>>>(x, pw1, pb1, pw2, pb2, p);

    // ---- layer 1 ----
    hipMemsetAsync(hb0, 0, (size_t)3*32768*sizeof(float), stream);
    for (int c = 0; c < NCH; c++) {
        const int t0 = c * TCH;
        gemm_chunk<256><<<dim3(64, 50), 256, 0, stream>>>(p, wx1, xwc, t0);
        for (int tt = 0; tt < TCH; tt++) {
            const int t = t0 + tt;
            float* hin = (t & 1) ? hb1 : hb0;
            float* hou = (t & 1) ? hb0 : hb1;
            lstm_step<<<256, 256, 0, stream>>>(whT1, xwc, a1, b11, b21, bias1,
                                               hin, hou, cb, hseq, t, tt);
        }
    }

    // ---- layer 2 ----
    hipMemsetAsync(hb0, 0, (size_t)3*32768*sizeof(float), stream);
    for (int c = 0; c < NCH; c++) {
        const int t0 = c * TCH;
        gemm_chunk<1024><<<dim3(64, 50), 256, 0, stream>>>(hseq, wx2, xwc, t0);
        for (int tt = 0; tt < TCH; tt++) {
            const int t = t0 + tt;
            float* hin = (t & 1) ? hb1 : hb0;
            float* hou = (t & 1) ? hb0 : hb1;
            lstm_step<<<256, 256, 0, stream>>>(whT2, xwc, a2, b12, b22, bias2,
                                               hin, hou, cb, hseq, t, tt);
        }
    }

    final_kernel<<<400, 256, 0, stream>>>(hseq, fw, fb, sw, sb, out);
}

// Round 11
// 7297.392 us; speedup vs baseline: 7.9619x; 2.4011x over previous
//
#include <hip/hip_runtime.h>
#include <hip/hip_fp16.h>
#include <math.h>

#define B_   32
#define T_   400
#define BT_  12800
#define U_   1024
#define G4_  4096
#define TCH  100            // time-chunk length
#define NCH  4              // chunks per layer

typedef _Float16 f16x8 __attribute__((ext_vector_type(8)));
typedef float    f32x4 __attribute__((ext_vector_type(4)));

__device__ __forceinline__ float sigf(float x){ return 1.0f/(1.0f+expf(-x)); }
__device__ __forceinline__ int f2h2(float a, float b){
    __half2 h = __floats2half2_rn(a, b);
    return __builtin_bit_cast(int, h);
}
__device__ __forceinline__ f16x8 ldg8(const __half* p){
    return *reinterpret_cast<const f16x8*>(p);   // 16B aligned by construction
}

// Diagnostic: ws too small -> absmax ~1000 (distinct from silent-launch-fail 0.5)
__global__ __launch_bounds__(256) void ws_sentinel_kernel(float* __restrict__ out, int n)
{
    const int i = blockIdx.x * 256 + threadIdx.x;
    if (i < n) out[i] = 1000.0f;
}

// ---------------- one-time: WT[c][k] = (fp16) W[k][c], W is [rows][4096] ------
__global__ __launch_bounds__(256) void transpose_fp16_kernel(
    const float* __restrict__ W, __half* __restrict__ WT, int rowsTotal)
{
    __shared__ float tile[64][65];
    const int bx = blockIdx.x;   // 64 col tiles
    const int by = blockIdx.y;   // rowsTotal/64 row tiles
    const int tid = threadIdx.x;
    for (int i = tid; i < 1024; i += 256) {
        const int r  = i >> 4;
        const int c4 = (i & 15) * 4;
        float4 v = *(const float4*)&W[(by*64 + r)*G4_ + bx*64 + c4];
        tile[c4+0][r] = v.x; tile[c4+1][r] = v.y;
        tile[c4+2][r] = v.z; tile[c4+3][r] = v.w;
    }
    __syncthreads();
    for (int i = tid; i < 512; i += 256) {
        const int c  = i >> 3;
        const int r8 = (i & 7) * 8;
        int4 pk;
        pk.x = f2h2(tile[c][r8+0], tile[c][r8+1]);
        pk.y = f2h2(tile[c][r8+2], tile[c][r8+3]);
        pk.z = f2h2(tile[c][r8+4], tile[c][r8+5]);
        pk.w = f2h2(tile[c][r8+6], tile[c][r8+7]);
        *(int4*)&WT[(size_t)(bx*64 + c)*rowsTotal + by*64 + r8] = pk;
    }
}

// ---------------- prenet: p = relu(relu(x@pw1+pb1)@pw2+pb2), p stored fp16 ----
__global__ __launch_bounds__(256) void prenet_kernel(
    const float* __restrict__ x, const float* __restrict__ pw1, const float* __restrict__ pb1,
    const float* __restrict__ pw2, const float* __restrict__ pb2, __half* __restrict__ p)
{
    __shared__ float xs[32*80];
    __shared__ float ys[32*256];
    const int r0 = blockIdx.x * 32;
    const int tid = threadIdx.x;
    for (int i = tid; i < 32*80; i += 256) xs[i] = x[r0*80 + i];
    __syncthreads();
    const int j = tid;
    float acc[32];
    #pragma unroll
    for (int r=0;r<32;r++) acc[r] = pb1[j];
    for (int k=0;k<80;k++){
        float w = pw1[k*256 + j];
        #pragma unroll
        for (int r=0;r<32;r++) acc[r] += xs[r*80+k]*w;
    }
    #pragma unroll
    for (int r=0;r<32;r++) ys[r*256+j] = fmaxf(acc[r], 0.0f);
    __syncthreads();
    #pragma unroll
    for (int r=0;r<32;r++) acc[r] = pb2[j];
    for (int k=0;k<256;k++){
        float w = pw2[k*256 + j];
        #pragma unroll
        for (int r=0;r<32;r++) acc[r] += ys[r*256+k]*w;
    }
    #pragma unroll
    for (int r=0;r<32;r++) p[(r0+r)*256 + j] = __float2half_rn(fmaxf(acc[r], 0.0f));
}

// chunk-local row (0..3199) -> global row in [12800] (b*400 + t0 + tt)
__device__ __forceinline__ int groww(int l, int t0){
    const int bb = l / TCH;
    const int tt = l - bb*TCH;
    return bb*T_ + t0 + tt;
}

// ---------------- MFMA GEMM: xwc[3200,4096] = A_rows(chunk)[3200,K] @ wxT^T ---
// A fp16 [12800][K] (global rows); BT fp16 [4096][K] (wx transposed).
// 64x64 tile / block, 4 waves, each wave 32x32 (2x2 MFMA tiles), LDS-free.
template<int K>
__global__ __launch_bounds__(256) void gemm_mfma(
    const __half* __restrict__ A, const __half* __restrict__ BT,
    __half* __restrict__ C, int t0)
{
    const int tid  = threadIdx.x;
    const int wid  = tid >> 6;
    const int lane = tid & 63;
    const int lr   = lane & 15;
    const int kg   = lane >> 4;          // k-group 0..3 (8 fp16 each)
    const int wrow = wid >> 1;           // 0..1
    const int wcol = wid & 1;            // 0..1
    const int row0 = blockIdx.y*64 + wrow*32;   // chunk-local
    const int col0 = blockIdx.x*64 + wcol*32;

    const int gr0 = groww(row0 + lr,      t0);
    const int gr1 = groww(row0 + 16 + lr, t0);
    const __half* a0p = &A[(size_t)gr0*K + kg*8];
    const __half* a1p = &A[(size_t)gr1*K + kg*8];
    const __half* b0p = &BT[(size_t)(col0 + lr)*K      + kg*8];
    const __half* b1p = &BT[(size_t)(col0 + 16 + lr)*K + kg*8];

    f32x4 acc00={0,0,0,0}, acc01={0,0,0,0}, acc10={0,0,0,0}, acc11={0,0,0,0};
    for (int k0 = 0; k0 < K; k0 += 32) {
        const f16x8 a0 = ldg8(a0p + k0);
        const f16x8 a1 = ldg8(a1p + k0);
        const f16x8 b0 = ldg8(b0p + k0);
        const f16x8 b1 = ldg8(b1p + k0);
        acc00 = __builtin_amdgcn_mfma_f32_16x16x32_f16(a0, b0, acc00, 0, 0, 0);
        acc01 = __builtin_amdgcn_mfma_f32_16x16x32_f16(a0, b1, acc01, 0, 0, 0);
        acc10 = __builtin_amdgcn_mfma_f32_16x16x32_f16(a1, b0, acc10, 0, 0, 0);
        acc11 = __builtin_amdgcn_mfma_f32_16x16x32_f16(a1, b1, acc11, 0, 0, 0);
    }
    // D layout: row_in_tile = kg*4 + r, col_in_tile = lr  (C rows are chunk-LOCAL)
    #pragma unroll
    for (int r = 0; r < 4; r++) {
        const int rA = row0 + kg*4 + r, rB = row0 + 16 + kg*4 + r;
        const int cA = col0 + lr,       cB = col0 + 16 + lr;
        C[(size_t)rA*G4_ + cA] = __float2half_rn(acc00[r]);
        C[(size_t)rA*G4_ + cB] = __float2half_rn(acc01[r]);
        C[(size_t)rB*G4_ + cA] = __float2half_rn(acc10[r]);
        C[(size_t)rB*G4_ + cB] = __float2half_rn(acc11[r]);
    }
}

// ---------------- one MI-LSTM step (MFMA) ----------------
// 256 blocks x 256 thr (4 waves). Block owns 16 logical cols lc=g*4+j
// (units bu0..bu0+3 x 4 gates). hw[32 b x 16 lc] = h[32x1024] @ whT-slice^T.
// A-frags read DIRECTLY from fp16 h rows (seq at t-1, or zero buffer at t=0);
// B-frags direct from whT global (L2-hot). 4 waves split K; LDS reduce;
// fp32 gate/zoneout epilogue (carry via fp32 hprev/hout, c fp32 in place).
__global__ __launch_bounds__(256) void lstm_step(
    const __half* __restrict__ whT,   // [4096][1024] fp16
    const __half* __restrict__ xwc,   // [3200][4096] fp16, row = b*100 + tr
    const float* __restrict__ aP,  const float* __restrict__ b1P,
    const float* __restrict__ b2P, const float* __restrict__ biasP,
    const __half* __restrict__ hA,    // fp16 h source rows
    int rstride, int roff,            // row(b) = (b*rstride + roff)*U_
    const float* __restrict__ hprev,  // [32][1024] f32 carried h
    float* __restrict__ hout,         // [32][1024] f32
    float* __restrict__ c_st,         // [32][1024] f32
    __half* __restrict__ seq,         // [12800][1024] fp16
    int t, int tr)
{
    __shared__ float pt[4][32][17];
    const int tid  = threadIdx.x;
    const int wid  = tid >> 6;
    const int lane = tid & 63;
    const int lr   = lane & 15;
    const int kg   = lane >> 4;
    const int bu0  = blockIdx.x * 4;

    // B col for this lane: lc = lr -> whT row g*1024 + bu0 + j
    const __half* bp  = &whT[(size_t)((lr>>2)*U_ + bu0 + (lr&3))*U_ + wid*256 + kg*8];
    const __half* a0p = &hA[(size_t)(lr*rstride        + roff)*U_ + wid*256 + kg*8];
    const __half* a1p = &hA[(size_t)((lr+16)*rstride   + roff)*U_ + wid*256 + kg*8];

    f32x4 acc0={0,0,0,0}, acc1={0,0,0,0};
    #pragma unroll
    for (int ks = 0; ks < 8; ks++) {
        const f16x8 b  = ldg8(bp  + ks*32);
        const f16x8 a0 = ldg8(a0p + ks*32);
        const f16x8 a1 = ldg8(a1p + ks*32);
        acc0 = __builtin_amdgcn_mfma_f32_16x16x32_f16(a0, b, acc0, 0, 0, 0);
        acc1 = __builtin_amdgcn_mfma_f32_16x16x32_f16(a1, b, acc1, 0, 0, 0);
    }
    #pragma unroll
    for (int r = 0; r < 4; r++) {
        pt[wid][kg*4 + r][lr]      = acc0[r];
        pt[wid][16 + kg*4 + r][lr] = acc1[r];
    }
    __syncthreads();

    if (tid < 128) {
        const int bb = tid >> 2;
        const int j  = tid & 3;
        const int u  = bu0 + j;
        float hw[4];
        #pragma unroll
        for (int g = 0; g < 4; g++) {
            const int lc = g*4 + j;
            hw[g] = pt[0][bb][lc] + pt[1][bb][lc] + pt[2][bb][lc] + pt[3][bb][lc];
        }
        const __half* xwrow = &xwc[(size_t)(bb*TCH + tr) * G4_];
        const float x_i = __half2float(xwrow[0*U_ + u]);
        const float x_f = __half2float(xwrow[1*U_ + u]);
        const float x_g = __half2float(xwrow[2*U_ + u]);
        const float x_o = __half2float(xwrow[3*U_ + u]);
        const int ci = 0*U_+u, cf = 1*U_+u, cg = 2*U_+u, co = 3*U_+u;
        const float z_i = aP[ci]*x_i*hw[0] + b1P[ci]*x_i + b2P[ci]*hw[0] + biasP[ci];
        const float z_f = aP[cf]*x_f*hw[1] + b1P[cf]*x_f + b2P[cf]*hw[1] + biasP[cf];
        const float z_g = aP[cg]*x_g*hw[2] + b1P[cg]*x_g + b2P[cg]*hw[2] + biasP[cg];
        const float z_o = aP[co]*x_o*hw[3] + b1P[co]*x_o + b2P[co]*hw[3] + biasP[co];
        const float c_old  = c_st[bb*U_ + u];
        const float c_new  = sigf(z_f)*c_old + sigf(z_i)*tanhf(z_g);
        const float h_new  = sigf(z_o)*tanhf(c_new);
        const float c_outv = 0.1f*c_old + 0.9f*c_new;
        const float h_pv   = hprev[bb*U_ + u];
        const float h_outv = 0.1f*h_pv + 0.9f*h_new;
        c_st[bb*U_ + u]  = c_outv;
        hout[bb*U_ + u]  = h_outv;
        seq[(size_t)(bb*T_ + t)*U_ + u] = __float2half_rn(h_outv);
    }
}

// ---------------- final: out = concat(h2@fw+fb, sigmoid(h2@sw+sb)) -------------
__global__ __launch_bounds__(256) void final_kernel(
    const __half* __restrict__ h2, const float* __restrict__ fw, const float* __restrict__ fb,
    const float* __restrict__ sw, const float* __restrict__ sb, float* __restrict__ out)
{
    __shared__ float hs2[32*1028];
    const int r0 = blockIdx.x * 32;
    const int tid = threadIdx.x;
    for (int i = tid; i < 8192; i += 256) {
        const int r = i >> 8;
        const int k = (i & 255) * 4;
        const __half2* hp = (const __half2*)&h2[(size_t)(r0+r)*1024 + k];
        const float2 f0 = __half22float2(hp[0]);
        const float2 f1 = __half22float2(hp[1]);
        hs2[r*1028 + k+0] = f0.x; hs2[r*1028 + k+1] = f0.y;
        hs2[r*1028 + k+2] = f1.x; hs2[r*1028 + k+3] = f1.y;
    }
    __syncthreads();
    const int j = tid;
    if (j < 161) {
        const bool is_stop = (j == 160);
        float acc[32];
        const float bias = is_stop ? sb[0] : fb[j];
        #pragma unroll
        for (int r=0;r<32;r++) acc[r] = bias;
        for (int k=0;k<1024;k++){
            const float w = is_stop ? sw[k] : fw[k*160 + j];
            #pragma unroll
            for (int r=0;r<32;r++) acc[r] += hs2[r*1028 + k] * w;
        }
        #pragma unroll
        for (int r=0;r<32;r++){
            float v = acc[r];
            if (is_stop) v = sigf(v);
            out[(size_t)(r0+r)*161 + j] = v;
        }
    }
}

extern "C" void kernel_launch(void* const* d_in, const int* in_sizes, int n_in,
                              void* d_out, int out_size, void* d_ws, size_t ws_size,
                              hipStream_t stream)
{
    const float* x    = (const float*)d_in[0];
    const float* pw1  = (const float*)d_in[1];
    const float* pb1  = (const float*)d_in[2];
    const float* pw2  = (const float*)d_in[3];
    const float* pb2  = (const float*)d_in[4];
    const float* wx1  = (const float*)d_in[5];
    const float* wh1  = (const float*)d_in[6];
    const float* a1   = (const float*)d_in[7];
    const float* b11  = (const float*)d_in[8];
    const float* b21  = (const float*)d_in[9];
    const float* bias1= (const float*)d_in[10];
    const float* wx2  = (const float*)d_in[11];
    const float* wh2  = (const float*)d_in[12];
    const float* a2   = (const float*)d_in[13];
    const float* b12  = (const float*)d_in[14];
    const float* b22  = (const float*)d_in[15];
    const float* bias2= (const float*)d_in[16];
    const float* sw   = (const float*)d_in[17];
    const float* sb   = (const float*)d_in[18];
    const float* fw   = (const float*)d_in[19];
    const float* fb   = (const float*)d_in[20];
    float* out = (float*)d_out;

    // ws layout (bytes); total = 86,704,128 (~82.7 MiB)
    char* base = (char*)d_ws;
    __half* hseq = (__half*)(base);                    // 26,214,400
    __half* xwc  = (__half*)(base + 26214400);         // 26,214,400
    __half* p    = (__half*)(base + 52428800);         //  6,553,600
    float*  hb0  = (float*) (base + 58982400);         //    131,072
    float*  hb1  = (float*) (base + 59113472);         //    131,072
    float*  cb   = (float*) (base + 59244544);         //    131,072
    __half* whT1 = (__half*)(base + 59375616);         //  8,388,608
    __half* whT2 = (__half*)(base + 67764224);         //  8,388,608
    __half* wxT1 = (__half*)(base + 76152832);         //  2,097,152
    __half* wxT2 = (__half*)(base + 78249984);         //  8,388,608
    __half* h16z = (__half*)(base + 86638592);         //     65,536 -> 86,704,128
    const size_t NEED = 86704128;
    if (ws_size < NEED) {
        ws_sentinel_kernel<<<(out_size + 255) / 256, 256, 0, stream>>>(out, out_size);
        return;
    }

    // one-time weight prep
    transpose_fp16_kernel<<<dim3(64,16), 256, 0, stream>>>(wh1, whT1, 1024);
    transpose_fp16_kernel<<<dim3(64,16), 256, 0, stream>>>(wh2, whT2, 1024);
    transpose_fp16_kernel<<<dim3(64, 4), 256, 0, stream>>>(wx1, wxT1, 256);
    transpose_fp16_kernel<<<dim3(64,16), 256, 0, stream>>>(wx2, wxT2, 1024);
    hipMemsetAsync(h16z, 0, 65536, stream);

    prenet_kernel<<<400, 256, 0, stream>>>(x, pw1, pb1, pw2, pb2, p);

    // ---- layer 1 ----
    hipMemsetAsync(hb0, 0, (size_t)3*32768*sizeof(float), stream);
    for (int c = 0; c < NCH; c++) {
        const int t0 = c * TCH;
        gemm_mfma<256><<<dim3(64, 50), 256, 0, stream>>>(p, wxT1, xwc, t0);
        for (int tt = 0; tt < TCH; tt++) {
            const int t = t0 + tt;
            float* hin = (t & 1) ? hb1 : hb0;
            float* hou = (t & 1) ? hb0 : hb1;
            const __half* hA = (t == 0) ? h16z : hseq;
            const int rs = (t == 0) ? 1 : T_;
            const int ro = (t == 0) ? 0 : (t - 1);
            lstm_step<<<256, 256, 0, stream>>>(whT1, xwc, a1, b11, b21, bias1,
                                               hA, rs, ro, hin, hou, cb, hseq, t, tt);
        }
    }

    // ---- layer 2 (GEMM reads h1 chunk from hseq, steps overwrite with h2) ----
    hipMemsetAsync(hb0, 0, (size_t)3*32768*sizeof(float), stream);
    for (int c = 0; c < NCH; c++) {
        const int t0 = c * TCH;
        gemm_mfma<1024><<<dim3(64, 50), 256, 0, stream>>>(hseq, wxT2, xwc, t0);
        for (int tt = 0; tt < TCH; tt++) {
            const int t = t0 + tt;
            float* hin = (t & 1) ? hb1 : hb0;
            float* hou = (t & 1) ? hb0 : hb1;
            const __half* hA = (t == 0) ? h16z : hseq;
            const int rs = (t == 0) ? 1 : T_;
            const int ro = (t == 0) ? 0 : (t - 1);
            lstm_step<<<256, 256, 0, stream>>>(whT2, xwc, a2, b12, b22, bias2,
                                               hA, rs, ro, hin, hou, cb, hseq, t, tt);
        }
    }

    final_kernel<<<400, 256, 0, stream>>>(hseq, fw, fb, sw, sb, out);
}